// Round 3
// baseline (148.676 us; speedup 1.0000x reference)
//
#include <hip/hip_runtime.h>

typedef unsigned int u32;
typedef unsigned char u8;
typedef unsigned long long u64;

// Problem constants
#define DIMS   10000
#define LEVELS 100
#define SSIZE  617
#define SPAD   624        // padded s (multiple of 2; rows 617..623 are zero)
#define NCLS   26
#define BATCH  32
#define WORDS  313        // ceil(10000/32) sign-bit words per row
#define WPITCH 320        // padded word pitch (enc, part)
#define DPITCH 10240      // WPITCH*32 byte-count pitch per (slot,b)
#define NTILE  5          // d-tiles of 64 words (2048 dims)
#define MAXNCH 52

// ws layout (bytes)
#define OFF_OFFB 0u         //  624*32*4   = 79,872
#define OFF_IDB  0x20000u   //  624*313*4  = 781,248
#define OFF_LVB  0xE0000u   //  100*313*4  = 125,200
#define OFF_ENC  0x100000u  //  32*320*4   = 40,960
#define OFF_P8   0x110000u  //  nch*32*10240 bytes
#define SLOT_BYTES ((size_t)BATCH * DPITCH)   // 327,680

#define PACK_WAVES ((SPAD + LEVELS) * 157)    // 113,668
#define PACK_BLOCKS ((PACK_WAVES + 3) / 4)    // 28,417
#define MISC_BLOCKS ((SPAD * BATCH + 255) / 256) // 78

// ---------------------------------------------------------------------------
// K1: pack id_w / lvl_w sign bits via __ballot (64 dims -> 2 u32 per wave);
// quantize x -> LDS byte offsets (transposed [s][b], pad s -> zero row 100);
// zero d_out.
// ---------------------------------------------------------------------------
__global__ __launch_bounds__(256) void k_pack(const float* __restrict__ x,
                                              const float* __restrict__ idw,
                                              const float* __restrict__ lvw,
                                              u32* __restrict__ idb,
                                              u32* __restrict__ lvb,
                                              u32* __restrict__ offb,
                                              float* __restrict__ out)
{
    int bx = blockIdx.x;
    int tid = threadIdx.x;
    if (bx < PACK_BLOCKS) {
        int wave = tid >> 6, lane = tid & 63;
        int wt = bx * 4 + wave;
        if (wt >= PACK_WAVES) return;          // wave-uniform exit
        int isLvl = wt >= SPAD * 157;
        int wt2 = isLvl ? wt - SPAD * 157 : wt;
        int r = wt2 / 157;
        int g = wt2 - r * 157;
        int d = g * 64 + lane;
        float v = 1.0f;                        // pad -> bit 0
        if (isLvl) {
            if (d < DIMS) v = lvw[(size_t)r * DIMS + d];
        } else {
            if (r < SSIZE && d < DIMS) v = idw[(size_t)r * DIMS + d];
        }
        u64 m = __ballot(v < 0.0f);            // bit i = lane i = dim d0+i
        if (lane == 0) {
            u32* dst = (isLvl ? lvb : idb) + (size_t)r * WORDS + 2 * g;
            dst[0] = (u32)m;
            if (2 * g + 1 < WORDS) dst[1] = (u32)(m >> 32);
        }
    } else {
        int t2 = (bx - PACK_BLOCKS) * 256 + tid;
        if (t2 < SPAD * BATCH) {
            int s = t2 >> 5, b = t2 & 31;
            u32 off = LEVELS * 256u;           // pad s -> zero row
            if (s < SSIZE) {
                float v = x[b * SSIZE + s];
                float r = rintf(v * (float)(LEVELS - 1));  // RTE = jnp.round
                int q = (int)r;
                q = q < 0 ? 0 : (q > LEVELS - 1 ? LEVELS - 1 : q);
                off = (u32)q * 256u;           // LDS row byte offset
            }
            offb[s * BATCH + b] = off;
        }
        if (t2 < BATCH * NCLS) out[t2] = 0.0f;
    }
}

// ---------------------------------------------------------------------------
// K2: bit-sliced bind+count. Block = 2048 dims (64 words, lane=word) x 32 b
// (4 waves x 8 b). Level-bit tile (101 rows x 256 B, row 100 = zeros) in LDS.
// Per s-pair per b: 2 ds_read_b32 + XOR + full-adder + ripple into 5 carry
// planes (chunk <= 62 -> no overflow). End: spread planes -> u8 counts.
// ---------------------------------------------------------------------------
__global__ __launch_bounds__(256) void k_bind(const u32* __restrict__ idb,
                                              const u32* __restrict__ lvb,
                                              const u32* __restrict__ offb,
                                              u32* __restrict__ part,
                                              int chunk)
{
    __shared__ u32 tile[(LEVELS + 1) * 64];    // 25.9 KB
    const int W0 = blockIdx.x * 64;
    const int slot = blockIdx.y;
    const int tid = threadIdx.x;

    for (int t = tid; t < (LEVELS + 1) * 64; t += 256) {
        int r = t >> 6, w = t & 63;
        u32 v = 0;
        if (r < LEVELS && (W0 + w) < WORDS) v = lvb[(size_t)r * WORDS + W0 + w];
        tile[t] = v;                           // row 100 stays 0
    }
    __syncthreads();

    const int lane = tid & 63;
    const int B0 = __builtin_amdgcn_readfirstlane((tid >> 6) * 8);
    const int wq = W0 + lane;
    const bool wv = wq < WORDS;
    const int sBeg = slot * chunk;
    const int sEnd = min(SPAD, sBeg + chunk);  // even count (all even)

    u32 ones[8], c0[8], c1[8], c2[8], c3[8], c4[8];
#pragma unroll
    for (int b = 0; b < 8; ++b) { ones[b]=0; c0[b]=0; c1[b]=0; c2[b]=0; c3[b]=0; c4[b]=0; }

    for (int s = sBeg; s < sEnd; s += 2) {
        u32 u1 = 0, u2 = 0;
        if (wv) {
            u1 = idb[(size_t)s * WORDS + wq];
            u2 = idb[(size_t)(s + 1) * WORDS + wq];
        }
        const u32* o1 = offb + s * BATCH + B0;   // wave-uniform -> s_load
        const u32* o2 = o1 + BATCH;
#pragma unroll
        for (int b = 0; b < 8; ++b) {
            u32 l1 = tile[(o1[b] >> 2) + lane];  // stride-1 -> conflict-free
            u32 l2 = tile[(o2[b] >> 2) + lane];
            u32 x1 = u1 ^ l1, x2 = u2 ^ l2;
            u32 t0 = x1 ^ x2;
            u32 sum = ones[b] ^ t0;
            u32 car = (x1 & x2) | (ones[b] & t0);
            ones[b] = sum;
            u32 t;
            t = c0[b] & car; c0[b] ^= car; car = t;
            t = c1[b] & car; c1[b] ^= car; car = t;
            t = c2[b] & car; c2[b] ^= car; car = t;
            t = c3[b] & car; c3[b] ^= car; car = t;
            c4[b] ^= car;                        // counts <= 62: no overflow
        }
    }

    // plane -> byte-count extraction: bit j of plane w -> byte j bit w.
#pragma unroll
    for (int b = 0; b < 8; ++b) {
        u32* dst = part + ((size_t)(slot * BATCH + B0 + b) * DPITCH + (size_t)wq * 32) / 4;
        u32 o[8];
#pragma unroll
        for (int g = 0; g < 8; ++g) {
            int sh = 4 * g;
            u32 n;
            n  =  (((ones[b] >> sh) & 0xFu) * 0x00204081u) & 0x01010101u;
            n |= ((((c0[b]  >> sh) & 0xFu) * 0x00204081u) & 0x01010101u) << 1;
            n |= ((((c1[b]  >> sh) & 0xFu) * 0x00204081u) & 0x01010101u) << 2;
            n |= ((((c2[b]  >> sh) & 0xFu) * 0x00204081u) & 0x01010101u) << 3;
            n |= ((((c3[b]  >> sh) & 0xFu) * 0x00204081u) & 0x01010101u) << 4;
            n |= ((((c4[b]  >> sh) & 0xFu) * 0x00204081u) & 0x01010101u) << 5;
            o[g] = n;
        }
        *(uint4*)(dst)     = make_uint4(o[0], o[1], o[2], o[3]);
        *(uint4*)(dst + 4) = make_uint4(o[4], o[5], o[6], o[7]);
    }
}

// ---------------------------------------------------------------------------
// K3: sum u8 slot partials per (b,d), threshold (enc=+1 <=> count<=308,
// multiset = 617-2*count is odd -> never 0), ballot-pack enc bits.
// ---------------------------------------------------------------------------
__global__ __launch_bounds__(256) void k_enc(const u32* __restrict__ part,
                                             u32* __restrict__ enc, int nch)
{
    const u8* p8 = (const u8*)part;
    const int b = blockIdx.y;
    const int d = blockIdx.x * 256 + threadIdx.x;   // < 10240
    int sum = 0;
    for (int c = 0; c < nch; ++c)
        sum += p8[(size_t)(c * BATCH + b) * DPITCH + d];
    u64 m = __ballot(sum <= 308);
    if ((threadIdx.x & 63) == 0) {
        int w = d >> 5;                             // even, <= 318
        enc[b * WPITCH + w]     = (u32)m;
        enc[b * WPITCH + w + 1] = (u32)(m >> 32);
    }
}

// ---------------------------------------------------------------------------
// K4: logit[b][c] = sum_d (+-1)*W[c,d]. Block per (c, 40-word group); thread
// = (b, seg); W row read once per group (1.04 MB total), enc from L1/L2.
// ---------------------------------------------------------------------------
__global__ __launch_bounds__(256) void k_logit(const u32* __restrict__ enc,
                                               const float* __restrict__ W,
                                               float* __restrict__ out)
{
    const int c = blockIdx.x;          // 26
    const int q = blockIdx.y;          // 8 groups of 40 words
    const int t = threadIdx.x;
    const int b = t & 31;
    const int seg = t >> 3 >> 2;       // t>>5: 0..7
    const u32* eb = enc + b * WPITCH;
    float acc = 0.0f;
    for (int w = q * 40; w < q * 40 + 40; ++w) {
        u32 ew = eb[w];
        int d = w * 32 + seg;
#pragma unroll
        for (int k = 0; k < 4; ++k, d += 8) {
            if (d < DIMS) {
                float wt = W[(size_t)c * DIMS + d];
                acc += ((ew >> (d & 31)) & 1u) ? wt : -wt;
            }
        }
    }
    acc += __shfl_xor(acc, 32);        // fold seg pairs within wave
    if ((t & 63) < 32) atomicAdd(out + b * NCLS + c, acc);
}

// ---------------------------------------------------------------------------
extern "C" void kernel_launch(void* const* d_in, const int* in_sizes, int n_in,
                              void* d_out, int out_size, void* d_ws, size_t ws_size,
                              hipStream_t stream)
{
    const float* x   = (const float*)d_in[0];  // (32, 617)
    const float* idw = (const float*)d_in[1];  // (617, 10000)
    const float* lvw = (const float*)d_in[2];  // (100, 10000)
    const float* W   = (const float*)d_in[3];  // (26, 10000)
    float* out = (float*)d_out;                // (32, 26)

    char* ws = (char*)d_ws;
    u32* offb = (u32*)(ws + OFF_OFFB);
    u32* idb  = (u32*)(ws + OFF_IDB);
    u32* lvb  = (u32*)(ws + OFF_LVB);
    u32* enc  = (u32*)(ws + OFF_ENC);
    u32* part = (u32*)(ws + OFF_P8);

    size_t avail = ws_size > OFF_P8 ? ws_size - OFF_P8 : 0;
    int nch = (int)(avail / SLOT_BYTES);
    if (nch > MAXNCH) nch = MAXNCH;
    if (nch < 1) nch = 1;
    int chunk = (SPAD + nch - 1) / nch;
    chunk = (chunk + 1) & ~1;                  // even (pairs), <=62 if nch>=11
    nch = (SPAD + chunk - 1) / chunk;

    k_pack<<<PACK_BLOCKS + MISC_BLOCKS, 256, 0, stream>>>(x, idw, lvw, idb, lvb, offb, out);

    dim3 g2(NTILE, nch);                       // (5, 52) default
    k_bind<<<g2, 256, 0, stream>>>(idb, lvb, offb, part, chunk);

    dim3 g3(40, BATCH);                        // 1280 blocks
    k_enc<<<g3, 256, 0, stream>>>(part, enc, nch);

    dim3 g4(NCLS, 8);                          // 208 blocks
    k_logit<<<g4, 256, 0, stream>>>(enc, W, out);
}